// Round 5
// baseline (884.083 us; speedup 1.0000x reference)
//
#include <hip/hip_runtime.h>

// ---------------------------------------------------------------------------
// RPN head on gfx950: x --conv3x3(512->256)+relu--> h1 --conv3x3(256->256)+relu
//   --> h2 --1x1 heads (cls 18 / reg 36)--> softmax pairs --> out (B,H,W,9,6)
// R5: fat block. 512 thr, BM=256 (2 px rows) x BN=256, wave tile 64x128
// (2x4 of 32x32 MFMA) -> 6 LDS reads per 8 MFMAs (was 1:1). R3's proven
// conflict-free LDS geometry (stride-72 pad). Register-prefetch of next
// iter's globals during compute; ds_write after the read barrier.
// ---------------------------------------------------------------------------

typedef float f32x4  __attribute__((ext_vector_type(4)));
typedef float f32x16 __attribute__((ext_vector_type(16)));
typedef short bf16x8 __attribute__((ext_vector_type(8)));   // 8 bf16 = 4 VGPRs

union U16x8 { uint4 v; unsigned short s[8]; };

__device__ __forceinline__ unsigned short f2bf(float f) {
  union { float f; unsigned int u; } v; v.f = f;
  unsigned int r = v.u + 0x7FFFu + ((v.u >> 16) & 1u);   // RNE
  return (unsigned short)(r >> 16);
}

// ---- transpose + fp32->bf16: src[z][K][N] -> dst[z][N][K] ------------------
__global__ __launch_bounds__(256) void transpose_cvt(
    const float* __restrict__ src, unsigned short* __restrict__ dst,
    int K, int N) {
  __shared__ float t[32][33];
  const int tx = threadIdx.x, ty = threadIdx.y;     // 32 x 8
  const int k0 = blockIdx.x * 32, n0 = blockIdx.y * 32;
  const float* s = src + (size_t)blockIdx.z * K * N;
  unsigned short* d = dst + (size_t)blockIdx.z * N * K;
#pragma unroll
  for (int r = 0; r < 32; r += 8) {
    int k = k0 + ty + r, n = n0 + tx;
    t[ty + r][tx] = (k < K && n < N) ? s[(size_t)k * N + n] : 0.f;
  }
  __syncthreads();
#pragma unroll
  for (int r = 0; r < 32; r += 8) {
    int n = n0 + ty + r, k = k0 + tx;
    if (n < N && k < K) d[(size_t)n * K + k] = f2bf(t[tx][ty + r]);
  }
}

// ---- x (f32 NHWC) -> x_pad (bf16, [4][130][130][512], zero halo) -----------
__global__ __launch_bounds__(256) void convert_x(
    const float* __restrict__ x, unsigned short* __restrict__ xp) {
  int idx = blockIdx.x * 256 + threadIdx.x;       // 4*130*130*64 exactly
  int g = idx & 63;                                // 8-channel group
  int cell = idx >> 6;
  int xpix = cell % 130;
  int t = cell / 130;
  int ypix = t % 130;
  int b = t / 130;
  U16x8 u;
  if (xpix == 0 || xpix == 129 || ypix == 0 || ypix == 129) {
    u.v = make_uint4(0u, 0u, 0u, 0u);
  } else {
    const float* sp = x + ((size_t)((b * 128 + ypix - 1) * 128) + (xpix - 1)) * 512 + g * 8;
    float4 a = *(const float4*)sp;
    float4 c = *(const float4*)(sp + 4);
    u.s[0] = f2bf(a.x); u.s[1] = f2bf(a.y); u.s[2] = f2bf(a.z); u.s[3] = f2bf(a.w);
    u.s[4] = f2bf(c.x); u.s[5] = f2bf(c.y); u.s[6] = f2bf(c.z); u.s[7] = f2bf(c.w);
  }
  *(uint4*)(xp + (size_t)cell * 512 + g * 8) = u.v;
}

// ---- zero the halo of h1_pad: border cells only ----------------------------
__global__ __launch_bounds__(256) void zero_h1_borders(unsigned short* __restrict__ h1p) {
  int idx = blockIdx.x * 256 + threadIdx.x;        // 66048 exactly
  int g = idx & 31;
  int cell = idx >> 5;                             // 0..2063
  int b = cell / 516, c = cell % 516;
  int row, col;
  if (c < 130)      { row = 0;   col = c; }
  else if (c < 260) { row = 129; col = c - 130; }
  else { int e = c - 260; row = 1 + (e >> 1); col = (e & 1) * 129; }
  size_t ci = ((size_t)(b * 130) + row) * 130 + col;
  *(uint4*)(h1p + ci * 256 + g * 8) = make_uint4(0u, 0u, 0u, 0u);
}

// ---- 3x3 conv: fat-block implicit GEMM, bf16 MFMA 32x32x16, dx-merged ------
// Ap:  [4][130][130][CIN] bf16 (zero halo).  WT: [9][256][CIN] bf16 (B^T).
// MODE 0: out = h1_pad (interior).  MODE 1: flat NHWC.
// BM=256 (2 px rows), BN=256, BK=64; iter = (dy, ci0); 512 thr = 8 waves
// in 4(M)x2(N); wave tile 64x128 = 2x4 MFMAs of 32x32.
// Register-prefetch: iter+1's globals loaded to VGPRs during iter's compute.
template<int CIN, int MODE>
__global__ __launch_bounds__(512, 2) void conv3x3(
    const unsigned short* __restrict__ Ap,
    const unsigned short* __restrict__ WT,
    const float* __restrict__ bias,
    unsigned short* __restrict__ out) {
  constexpr int NC = CIN / 64;          // ci0 steps
  constexpr int NI = 3 * NC;            // total iterations (dy outer)
  __shared__ __align__(16) unsigned short As[260][72];     // 37,440 B
  __shared__ __align__(16) unsigned short Bs[3][256][72];  // 110,592 B
  const int tid  = threadIdx.x;
  const int wave = tid >> 6, lane = tid & 63;
  const int wm = wave >> 1, wn = wave & 1;   // 4 M-waves x 2 N-waves
  const int l31 = lane & 31, hi = lane >> 5;
  const int b  = blockIdx.x >> 6;            // batch
  const int y0 = (blockIdx.x & 63) * 2;      // output row pair base

  uint4 pa[4], pa_t, pb[12];
  const bool tail = (tid < 32);

  // issue global loads for iteration `it` into registers (no LDS yet)
  auto issueLoads = [&](int it) {
    int dy = it / NC, ci0 = (it - dy * NC) * 64;
    // A: rows r2=0..259 -> (p = r2>=130, x' = r2-130p), 8 segs of 16B
#pragma unroll
    for (int t = 0; t < 4; ++t) {
      int s = t * 512 + tid;
      int r2 = s >> 3, seg = s & 7;
      int p = (r2 >= 130) ? 1 : 0, xp = r2 - 130 * p;
      pa[t] = *(const uint4*)(Ap +
          (((size_t)(b * 130 + y0 + p + dy)) * 130 + xp) * CIN + ci0 + seg * 8);
    }
    if (tail) {
      int s = 2048 + tid;
      int r2 = s >> 3, seg = s & 7;
      int xp = r2 - 130;
      pa_t = *(const uint4*)(Ap +
          (((size_t)(b * 130 + y0 + 1 + dy)) * 130 + xp) * CIN + ci0 + seg * 8);
    }
    // B: 3 dx x 256 co x 8 segs = 6144 uint4
#pragma unroll
    for (int t = 0; t < 12; ++t) {
      int s = t * 512 + tid;
      int dx = s >> 11, rw = (s >> 3) & 255, seg = s & 7;
      pb[t] = *(const uint4*)(WT +
          (((size_t)(dy * 3 + dx)) * 256 + rw) * CIN + ci0 + seg * 8);
    }
  };
  // write prefetched registers into LDS (R3's conflict-free write pattern)
  auto writeLDS = [&]() {
#pragma unroll
    for (int t = 0; t < 4; ++t) {
      int s = t * 512 + tid;
      *(uint4*)&As[s >> 3][(s & 7) * 8] = pa[t];
    }
    if (tail) {
      int s = 2048 + tid;
      *(uint4*)&As[s >> 3][(s & 7) * 8] = pa_t;
    }
#pragma unroll
    for (int t = 0; t < 12; ++t) {
      int s = t * 512 + tid;
      int dx = s >> 11, rw = (s >> 3) & 255, seg = s & 7;
      *(uint4*)&Bs[dx][rw][seg * 8] = pb[t];
    }
  };

  f32x16 acc[2][4] = {};

  issueLoads(0);
  writeLDS();
  __syncthreads();
  for (int it = 0; it < NI; ++it) {
    if (it + 1 < NI) issueLoads(it + 1);     // in-flight during compute
#pragma unroll
    for (int dx = 0; dx < 3; ++dx) {
#pragma unroll
      for (int ks = 0; ks < 4; ++ks) {       // K=16 sub-steps of BK=64
        bf16x8 af[2], bfr[4];
#pragma unroll
        for (int i = 0; i < 2; ++i) {
          int m = wm * 64 + i * 32 + l31;    // 0..255
          int p = m >> 7, xx = m & 127;
          af[i] = *(const bf16x8*)&As[p * 130 + xx + dx][ks * 16 + hi * 8];
        }
#pragma unroll
        for (int j = 0; j < 4; ++j) {
          int rw = wn * 128 + j * 32 + l31;  // 0..255
          bfr[j] = *(const bf16x8*)&Bs[dx][rw][ks * 16 + hi * 8];
        }
#pragma unroll
        for (int i = 0; i < 2; ++i)
#pragma unroll
          for (int j = 0; j < 4; ++j)
            acc[i][j] = __builtin_amdgcn_mfma_f32_32x32x16_bf16(af[i], bfr[j], acc[i][j], 0, 0, 0);
      }
    }
    __syncthreads();                         // all waves done reading LDS
    if (it + 1 < NI) writeLDS();             // waitcnt(prefetch) is ~free here
    __syncthreads();                         // LDS ready for next iter
  }

  // epilogue: 32x32 C/D: col = lane&31, row = (reg&3)+8*(reg>>2)+4*hi
#pragma unroll
  for (int i = 0; i < 2; ++i) {
#pragma unroll
    for (int j = 0; j < 4; ++j) {
      int n = wn * 128 + j * 32 + l31;
      float bb = bias[n];
#pragma unroll
      for (int reg = 0; reg < 16; ++reg) {
        int m = wm * 64 + i * 32 + (reg & 3) + 8 * (reg >> 2) + 4 * hi;
        int p = m >> 7, xx = m & 127;
        float v = fmaxf(acc[i][j][reg] + bb, 0.f);
        size_t off;
        if (MODE == 0)
          off = ((size_t)(b * 130 + y0 + p + 1) * 130 + (xx + 1)) * 256 + n;
        else
          off = ((size_t)((b * 128 + y0 + p) * 128 + xx)) * 256 + n;
        out[off] = f2bf(v);
      }
    }
  }
}

// ---- heads: h2[65536][256] x WhT[54(pad 64)][256] + bias, softmax pairs ----
__global__ __launch_bounds__(256) void heads_kernel(
    const unsigned short* __restrict__ h2,
    const unsigned short* __restrict__ WhT,
    const float* __restrict__ br, const float* __restrict__ bc,
    float* __restrict__ out) {
  __shared__ __align__(16) unsigned short As[64][264];
  const int tid = threadIdx.x;
  const int wave = tid >> 6, lane = tid & 63;
  const int quad = lane >> 4, l16 = lane & 15;
  const int pix0 = blockIdx.x * 64;
#pragma unroll
  for (int r = 0; r < 8; ++r) {
    int s = r * 256 + tid;
    int row = s >> 5, seg = s & 31;                  // 64 rows x 32 x 16B
    *(uint4*)&As[row][seg * 8] =
        *(const uint4*)(h2 + (size_t)(pix0 + row) * 256 + seg * 8);
  }
  __syncthreads();
  f32x4 acc[4] = {};
#pragma unroll
  for (int ks = 0; ks < 8; ++ks) {
    bf16x8 af = *(const bf16x8*)&As[wave * 16 + l16][ks * 32 + quad * 8];
#pragma unroll
    for (int j = 0; j < 4; ++j) {
      bf16x8 bfr = *(const bf16x8*)(WhT + (size_t)(j * 16 + l16) * 256 + ks * 32 + quad * 8);
      acc[j] = __builtin_amdgcn_mfma_f32_16x16x32_bf16(af, bfr, acc[j], 0, 0, 0);
    }
  }
#pragma unroll
  for (int j = 0; j < 4; ++j) {
    int n = j * 16 + l16;                            // head channel (cls 0-17, reg 18-53)
    float bias = 0.f;
    if (n < 18) bias = bc[n];
    else if (n < 54) bias = br[n - 18];
#pragma unroll
    for (int r = 0; r < 4; ++r) {
      int p = pix0 + wave * 16 + quad * 4 + r;       // pixel
      float v = acc[j][r] + bias;
      float partner = __shfl_xor(v, 1);              // cls pair (even,odd lanes)
      if (n < 18) {
        float mx = fmaxf(v, partner);
        float e0 = __expf(v - mx), e1 = __expf(partner - mx);
        int a = n >> 1, sl2 = n & 1;
        out[(size_t)p * 54 + a * 6 + sl2] = e0 / (e0 + e1);
      } else if (n < 54) {
        int rr = n - 18, a = rr >> 2, sl2 = (rr & 3) + 2;
        out[(size_t)p * 54 + a * 6 + sl2] = v;
      }
    }
  }
}

// ---------------------------------------------------------------------------
extern "C" void kernel_launch(void* const* d_in, const int* in_sizes, int n_in,
                              void* d_out, int out_size, void* d_ws, size_t ws_size,
                              hipStream_t stream) {
  const float* x  = (const float*)d_in[0];
  const float* W1 = (const float*)d_in[1];
  const float* b1 = (const float*)d_in[2];
  const float* W2 = (const float*)d_in[3];
  const float* b2 = (const float*)d_in[4];
  const float* Wr = (const float*)d_in[5];
  const float* br = (const float*)d_in[6];
  const float* Wc = (const float*)d_in[7];
  const float* bc = (const float*)d_in[8];
  float* out = (float*)d_out;

  // workspace carve-up (bytes)
  constexpr size_t XPAD_B  = 4ull * 130 * 130 * 512 * 2;   //  69,222,400
  constexpr size_t H1PAD_B = 4ull * 130 * 130 * 256 * 2;   //  34,611,200
  constexpr size_t H2_B    = 4ull * 128 * 128 * 256 * 2;   //  33,554,432
  constexpr size_t W1T_B   = 9ull * 256 * 512 * 2;         //   2,359,296
  constexpr size_t W2T_B   = 9ull * 256 * 256 * 2;         //   1,179,648
  char* ws = (char*)d_ws;
  unsigned short* x_pad  = (unsigned short*)(ws);
  unsigned short* h1_pad = (unsigned short*)(ws + XPAD_B);
  unsigned short* h2     = (unsigned short*)(ws + XPAD_B + H1PAD_B);
  unsigned short* W1T    = (unsigned short*)(ws + XPAD_B + H1PAD_B + H2_B);
  unsigned short* W2T    = (unsigned short*)(ws + XPAD_B + H1PAD_B + H2_B + W1T_B);
  unsigned short* WhT    = (unsigned short*)(ws + XPAD_B + H1PAD_B + H2_B + W1T_B + W2T_B);

  // zero the padded head-weight block (rows 54..63 are read by MFMA)
  hipMemsetAsync(WhT, 0, 64ull * 256 * 2, stream);
  // weight repacks (B^T, bf16)
  transpose_cvt<<<dim3(16, 8, 9), dim3(32, 8), 0, stream>>>(W1, W1T, 512, 256);
  transpose_cvt<<<dim3(8, 8, 9),  dim3(32, 8), 0, stream>>>(W2, W2T, 256, 256);
  transpose_cvt<<<dim3(8, 1, 1),  dim3(32, 8), 0, stream>>>(Wc, WhT, 256, 18);
  transpose_cvt<<<dim3(8, 2, 1),  dim3(32, 8), 0, stream>>>(Wr, WhT + 18 * 256, 256, 36);
  // input pad+convert, h1 halo zero (borders only)
  convert_x<<<16900, 256, 0, stream>>>(x, x_pad);
  zero_h1_borders<<<258, 256, 0, stream>>>(h1_pad);
  // conv1: 512ci -> h1_pad ; conv2: 256ci -> h2 flat.  256 blocks x 512 thr.
  conv3x3<512, 0><<<256, 512, 0, stream>>>(x_pad, W1T, b1, h1_pad);
  conv3x3<256, 1><<<256, 512, 0, stream>>>(h1_pad, W2T, b2, h2);
  // 1x1 heads + softmax + interleave
  heads_kernel<<<1024, 256, 0, stream>>>(h2, WhT, br, bc, out);
}

// Round 6
// 835.591 us; speedup vs baseline: 1.0580x; 1.0580x over previous
//
#include <hip/hip_runtime.h>

// ---------------------------------------------------------------------------
// RPN head on gfx950: x --conv3x3(512->256)+relu--> h1 --conv3x3(256->256)+relu
//   --> h2 --1x1 heads (cls 18 / reg 36)--> softmax pairs --> out (B,H,W,9,6)
// R6: BK=32 double-buffered K-loop, one barrier/iter. Prefetch next slice into
// 9 uint4 regs (no spill: acc=64), compute 24 MFMA from buf, ds_write buf^1,
// barrier. LDS unpadded + XOR block swizzle (blk^(row&3)) -> 2-way max (free),
// 65.8 KB dbuf -> 2 blocks/CU. R5 lesson: 128-reg acc + 68-reg prefetch spills.
// ---------------------------------------------------------------------------

typedef float f32x4  __attribute__((ext_vector_type(4)));
typedef float f32x16 __attribute__((ext_vector_type(16)));
typedef short bf16x8 __attribute__((ext_vector_type(8)));   // 8 bf16 = 4 VGPRs

union U16x8 { uint4 v; unsigned short s[8]; };

__device__ __forceinline__ unsigned short f2bf(float f) {
  union { float f; unsigned int u; } v; v.f = f;
  unsigned int r = v.u + 0x7FFFu + ((v.u >> 16) & 1u);   // RNE
  return (unsigned short)(r >> 16);
}

// ---- transpose + fp32->bf16: src[z][K][N] -> dst[z][N][K] ------------------
__global__ __launch_bounds__(256) void transpose_cvt(
    const float* __restrict__ src, unsigned short* __restrict__ dst,
    int K, int N) {
  __shared__ float t[32][33];
  const int tx = threadIdx.x, ty = threadIdx.y;     // 32 x 8
  const int k0 = blockIdx.x * 32, n0 = blockIdx.y * 32;
  const float* s = src + (size_t)blockIdx.z * K * N;
  unsigned short* d = dst + (size_t)blockIdx.z * N * K;
#pragma unroll
  for (int r = 0; r < 32; r += 8) {
    int k = k0 + ty + r, n = n0 + tx;
    t[ty + r][tx] = (k < K && n < N) ? s[(size_t)k * N + n] : 0.f;
  }
  __syncthreads();
#pragma unroll
  for (int r = 0; r < 32; r += 8) {
    int n = n0 + ty + r, k = k0 + tx;
    if (n < N && k < K) d[(size_t)n * K + k] = f2bf(t[tx][ty + r]);
  }
}

// ---- x (f32 NHWC) -> x_pad (bf16, [4][130][130][512], zero halo) -----------
__global__ __launch_bounds__(256) void convert_x(
    const float* __restrict__ x, unsigned short* __restrict__ xp) {
  int idx = blockIdx.x * 256 + threadIdx.x;       // 4*130*130*64 exactly
  int g = idx & 63;                                // 8-channel group
  int cell = idx >> 6;
  int xpix = cell % 130;
  int t = cell / 130;
  int ypix = t % 130;
  int b = t / 130;
  U16x8 u;
  if (xpix == 0 || xpix == 129 || ypix == 0 || ypix == 129) {
    u.v = make_uint4(0u, 0u, 0u, 0u);
  } else {
    const float* sp = x + ((size_t)((b * 128 + ypix - 1) * 128) + (xpix - 1)) * 512 + g * 8;
    float4 a = *(const float4*)sp;
    float4 c = *(const float4*)(sp + 4);
    u.s[0] = f2bf(a.x); u.s[1] = f2bf(a.y); u.s[2] = f2bf(a.z); u.s[3] = f2bf(a.w);
    u.s[4] = f2bf(c.x); u.s[5] = f2bf(c.y); u.s[6] = f2bf(c.z); u.s[7] = f2bf(c.w);
  }
  *(uint4*)(xp + (size_t)cell * 512 + g * 8) = u.v;
}

// ---- zero the halo of h1_pad: border cells only ----------------------------
__global__ __launch_bounds__(256) void zero_h1_borders(unsigned short* __restrict__ h1p) {
  int idx = blockIdx.x * 256 + threadIdx.x;        // 66048 exactly
  int g = idx & 31;
  int cell = idx >> 5;                             // 0..2063
  int b = cell / 516, c = cell % 516;
  int row, col;
  if (c < 130)      { row = 0;   col = c; }
  else if (c < 260) { row = 129; col = c - 130; }
  else { int e = c - 260; row = 1 + (e >> 1); col = (e & 1) * 129; }
  size_t ci = ((size_t)(b * 130) + row) * 130 + col;
  *(uint4*)(h1p + ci * 256 + g * 8) = make_uint4(0u, 0u, 0u, 0u);
}

// ---- 3x3 conv: dbuf BK=32 implicit GEMM, bf16 MFMA 32x32x16, dx-merged -----
// Ap:  [4][130][130][CIN] bf16 (zero halo).  WT: [9][256][CIN] bf16 (B^T).
// MODE 0: out = h1_pad (interior).  MODE 1: flat NHWC.
// BM=128 (one image row), BN=128, BK=32; iter=(dy,ci0); 24 MFMA/wave/iter.
// LDS rows = 32 halfs = 4 blocks of 16B; block blk stored at blk^(row&3).
template<int CIN, int MODE>
__global__ __launch_bounds__(256, 2) void conv3x3(
    const unsigned short* __restrict__ Ap,
    const unsigned short* __restrict__ WT,
    const float* __restrict__ bias,
    unsigned short* __restrict__ out) {
  constexpr int NC = CIN / 32;          // ci0 steps
  constexpr int NI = 3 * NC;            // total iterations (dy outer)
  __shared__ __align__(16) unsigned short As[2][130 * 32];      // 2 x  8,320 B
  __shared__ __align__(16) unsigned short Bs[2][3 * 128 * 32];  // 2 x 24,576 B
  const int tid  = threadIdx.x;
  const int wave = tid >> 6, lane = tid & 63;
  const int wm = wave >> 1, wn = wave & 1;
  const int l31 = lane & 31, hi = lane >> 5;
  const int gid = blockIdx.x;
  const int b = gid >> 8, y = (gid >> 1) & 127, nbase = (gid & 1) * 128;

  uint4 ra0, ra1, rat, rb[6];

  // global loads for iteration `it` into registers (kept in flight over compute)
  auto loadG = [&](int it) {
    int dy = it / NC, ci0 = (it - dy * NC) * 32;
    const unsigned short* Arow = Ap + ((size_t)(b * 130 + y + dy) * 130) * CIN + ci0;
    const unsigned short* Bt   = WT + ((size_t)(dy * 3) * 256 + nbase) * CIN + ci0;
    {
      int r = tid >> 2, blk = tid & 3;                    // rows 0..63
      ra0 = *(const uint4*)(Arow + (size_t)r * CIN + blk * 8);
    }
    {
      int s = 256 + tid;
      int r = s >> 2, blk = s & 3;                        // rows 64..127
      ra1 = *(const uint4*)(Arow + (size_t)r * CIN + blk * 8);
    }
    if (tid < 8) {
      int s = 512 + tid;
      int r = s >> 2, blk = s & 3;                        // rows 128,129
      rat = *(const uint4*)(Arow + (size_t)r * CIN + blk * 8);
    }
#pragma unroll
    for (int t = 0; t < 6; ++t) {
      int s = t * 256 + tid;                              // 1536 uint4
      int dx = s >> 9, r = (s >> 2) & 127, blk = s & 3;
      rb[t] = *(const uint4*)(Bt + ((size_t)dx * 256 + r) * CIN + blk * 8);
    }
  };
  // write prefetched regs into LDS buffer `buf` (XOR block swizzle)
  auto writeL = [&](int buf) {
    {
      int r = tid >> 2, blk = tid & 3;
      *(uint4*)&As[buf][r * 32 + ((blk ^ (r & 3)) * 8)] = ra0;
    }
    {
      int s = 256 + tid;
      int r = s >> 2, blk = s & 3;
      *(uint4*)&As[buf][r * 32 + ((blk ^ (r & 3)) * 8)] = ra1;
    }
    if (tid < 8) {
      int s = 512 + tid;
      int r = s >> 2, blk = s & 3;
      *(uint4*)&As[buf][r * 32 + ((blk ^ (r & 3)) * 8)] = rat;
    }
#pragma unroll
    for (int t = 0; t < 6; ++t) {
      int s = t * 256 + tid;
      int dx = s >> 9, r = (s >> 2) & 127, blk = s & 3;
      *(uint4*)&Bs[buf][(dx * 128 + r) * 32 + ((blk ^ (r & 3)) * 8)] = rb[t];
    }
  };

  f32x16 acc[2][2] = {};

  loadG(0);
  writeL(0);
  __syncthreads();
  int cur = 0;
  for (int it = 0; it < NI; ++it) {
    if (it + 1 < NI) loadG(it + 1);          // async under compute
#pragma unroll
    for (int dx = 0; dx < 3; ++dx) {
#pragma unroll
      for (int ks = 0; ks < 2; ++ks) {       // K=16 sub-steps of BK=32
        bf16x8 af[2], bfr[2];
#pragma unroll
        for (int i = 0; i < 2; ++i) {
          int r = wm * 64 + i * 32 + l31 + dx;
          int blk = (ks * 2 + hi) ^ (r & 3);
          af[i] = *(const bf16x8*)&As[cur][r * 32 + blk * 8];
        }
#pragma unroll
        for (int j = 0; j < 2; ++j) {
          int r = wn * 64 + j * 32 + l31;
          int blk = (ks * 2 + hi) ^ (r & 3);
          bfr[j] = *(const bf16x8*)&Bs[cur][(dx * 128 + r) * 32 + blk * 8];
        }
#pragma unroll
        for (int i = 0; i < 2; ++i)
#pragma unroll
          for (int j = 0; j < 2; ++j)
            acc[i][j] = __builtin_amdgcn_mfma_f32_32x32x16_bf16(af[i], bfr[j], acc[i][j], 0, 0, 0);
      }
    }
    if (it + 1 < NI) writeL(cur ^ 1);        // vmcnt wait covered by compute
    __syncthreads();
    cur ^= 1;
  }

  // epilogue: 32x32 C/D layout: col = lane&31, row = (reg&3)+8*(reg>>2)+4*hi
#pragma unroll
  for (int i = 0; i < 2; ++i) {
#pragma unroll
    for (int j = 0; j < 2; ++j) {
      int n = nbase + wn * 64 + j * 32 + l31;
      float bb = bias[n];
#pragma unroll
      for (int reg = 0; reg < 16; ++reg) {
        int m = wm * 64 + i * 32 + (reg & 3) + 8 * (reg >> 2) + 4 * hi;
        float v = fmaxf(acc[i][j][reg] + bb, 0.f);
        size_t off;
        if (MODE == 0)
          off = ((size_t)(b * 130 + y + 1) * 130 + (m + 1)) * 256 + n;
        else
          off = ((size_t)((b * 128 + y) * 128 + m)) * 256 + n;
        out[off] = f2bf(v);
      }
    }
  }
}

// ---- heads: h2[65536][256] x WhT[54(pad 64)][256] + bias, softmax pairs ----
__global__ __launch_bounds__(256) void heads_kernel(
    const unsigned short* __restrict__ h2,
    const unsigned short* __restrict__ WhT,
    const float* __restrict__ br, const float* __restrict__ bc,
    float* __restrict__ out) {
  __shared__ __align__(16) unsigned short As[64][264];
  const int tid = threadIdx.x;
  const int wave = tid >> 6, lane = tid & 63;
  const int quad = lane >> 4, l16 = lane & 15;
  const int pix0 = blockIdx.x * 64;
#pragma unroll
  for (int r = 0; r < 8; ++r) {
    int s = r * 256 + tid;
    int row = s >> 5, seg = s & 31;                  // 64 rows x 32 x 16B
    *(uint4*)&As[row][seg * 8] =
        *(const uint4*)(h2 + (size_t)(pix0 + row) * 256 + seg * 8);
  }
  __syncthreads();
  f32x4 acc[4] = {};
#pragma unroll
  for (int ks = 0; ks < 8; ++ks) {
    bf16x8 af = *(const bf16x8*)&As[wave * 16 + l16][ks * 32 + quad * 8];
#pragma unroll
    for (int j = 0; j < 4; ++j) {
      bf16x8 bfr = *(const bf16x8*)(WhT + (size_t)(j * 16 + l16) * 256 + ks * 32 + quad * 8);
      acc[j] = __builtin_amdgcn_mfma_f32_16x16x32_bf16(af, bfr, acc[j], 0, 0, 0);
    }
  }
#pragma unroll
  for (int j = 0; j < 4; ++j) {
    int n = j * 16 + l16;                            // head channel (cls 0-17, reg 18-53)
    float bias = 0.f;
    if (n < 18) bias = bc[n];
    else if (n < 54) bias = br[n - 18];
#pragma unroll
    for (int r = 0; r < 4; ++r) {
      int p = pix0 + wave * 16 + quad * 4 + r;       // pixel
      float v = acc[j][r] + bias;
      float partner = __shfl_xor(v, 1);              // cls pair (even,odd lanes)
      if (n < 18) {
        float mx = fmaxf(v, partner);
        float e0 = __expf(v - mx), e1 = __expf(partner - mx);
        int a = n >> 1, sl2 = n & 1;
        out[(size_t)p * 54 + a * 6 + sl2] = e0 / (e0 + e1);
      } else if (n < 54) {
        int rr = n - 18, a = rr >> 2, sl2 = (rr & 3) + 2;
        out[(size_t)p * 54 + a * 6 + sl2] = v;
      }
    }
  }
}

// ---------------------------------------------------------------------------
extern "C" void kernel_launch(void* const* d_in, const int* in_sizes, int n_in,
                              void* d_out, int out_size, void* d_ws, size_t ws_size,
                              hipStream_t stream) {
  const float* x  = (const float*)d_in[0];
  const float* W1 = (const float*)d_in[1];
  const float* b1 = (const float*)d_in[2];
  const float* W2 = (const float*)d_in[3];
  const float* b2 = (const float*)d_in[4];
  const float* Wr = (const float*)d_in[5];
  const float* br = (const float*)d_in[6];
  const float* Wc = (const float*)d_in[7];
  const float* bc = (const float*)d_in[8];
  float* out = (float*)d_out;

  // workspace carve-up (bytes)
  constexpr size_t XPAD_B  = 4ull * 130 * 130 * 512 * 2;   //  69,222,400
  constexpr size_t H1PAD_B = 4ull * 130 * 130 * 256 * 2;   //  34,611,200
  constexpr size_t H2_B    = 4ull * 128 * 128 * 256 * 2;   //  33,554,432
  constexpr size_t W1T_B   = 9ull * 256 * 512 * 2;         //   2,359,296
  constexpr size_t W2T_B   = 9ull * 256 * 256 * 2;         //   1,179,648
  char* ws = (char*)d_ws;
  unsigned short* x_pad  = (unsigned short*)(ws);
  unsigned short* h1_pad = (unsigned short*)(ws + XPAD_B);
  unsigned short* h2     = (unsigned short*)(ws + XPAD_B + H1PAD_B);
  unsigned short* W1T    = (unsigned short*)(ws + XPAD_B + H1PAD_B + H2_B);
  unsigned short* W2T    = (unsigned short*)(ws + XPAD_B + H1PAD_B + H2_B + W1T_B);
  unsigned short* WhT    = (unsigned short*)(ws + XPAD_B + H1PAD_B + H2_B + W1T_B + W2T_B);

  // zero the padded head-weight block (rows 54..63 are read by MFMA)
  hipMemsetAsync(WhT, 0, 64ull * 256 * 2, stream);
  // weight repacks (B^T, bf16)
  transpose_cvt<<<dim3(16, 8, 9), dim3(32, 8), 0, stream>>>(W1, W1T, 512, 256);
  transpose_cvt<<<dim3(8, 8, 9),  dim3(32, 8), 0, stream>>>(W2, W2T, 256, 256);
  transpose_cvt<<<dim3(8, 1, 1),  dim3(32, 8), 0, stream>>>(Wc, WhT, 256, 18);
  transpose_cvt<<<dim3(8, 2, 1),  dim3(32, 8), 0, stream>>>(Wr, WhT + 18 * 256, 256, 36);
  // input pad+convert, h1 halo zero (borders only)
  convert_x<<<16900, 256, 0, stream>>>(x, x_pad);
  zero_h1_borders<<<258, 256, 0, stream>>>(h1_pad);
  // convs: 1024 blocks, (y,n) adjacent in gid for L2 A-sharing
  conv3x3<512, 0><<<1024, 256, 0, stream>>>(x_pad, W1T, b1, h1_pad);
  conv3x3<256, 1><<<1024, 256, 0, stream>>>(h1_pad, W2T, b2, h2);
  // 1x1 heads + softmax + interleave
  heads_kernel<<<1024, 256, 0, stream>>>(h2, WhT, br, bc, out);
}